// Round 1
// baseline (196.759 us; speedup 1.0000x reference)
//
#include <hip/hip_runtime.h>
#include <math.h>

#define M_TOK 1024   // B*S
#define DM    2048   // d_model
#define NH    256    // heads
#define HD    8      // head dim
#define SCALE 0.35355339059327373f   // 1/sqrt(8)
#define LOG2E 1.4426950408889634f

typedef _Float16 f16x8 __attribute__((ext_vector_type(8)));
typedef _Float16 f16x4 __attribute__((ext_vector_type(4)));
typedef float    f32x4 __attribute__((ext_vector_type(4)));

#if defined(__has_builtin)
#  if __has_builtin(__builtin_amdgcn_exp2f)
#    define EXP2(x) __builtin_amdgcn_exp2f(x)
#  endif
#endif
#ifndef EXP2
#  define EXP2(x) exp2f(x)
#endif

// ---------------------------------------------------------------------------
// prep: z<4 -> weight fp32 [k][n] -> fp16 [n][k] (cast+transpose, 64x64 tiles);
//       z==4 -> x fp32 -> fp16 straight cast (8 elem/thread)
__global__ __launch_bounds__(256) void prep(
    const float* __restrict__ x, _Float16* __restrict__ xh,
    const float* __restrict__ W0, const float* __restrict__ W1,
    const float* __restrict__ W2, const float* __restrict__ W3,
    _Float16* __restrict__ T0, _Float16* __restrict__ T1,
    _Float16* __restrict__ T2, _Float16* __restrict__ T3)
{
    __shared__ float t[64][65];
    const int tid = threadIdx.x;
    const int z   = blockIdx.z;

    if (z == 4) {   // cast x
        const int i = (blockIdx.y * 32 + blockIdx.x) * 256 + tid;   // < 262144
        const float4 a = ((const float4*)x)[2 * i];
        const float4 b = ((const float4*)x)[2 * i + 1];
        f16x8 v;
        v[0] = (_Float16)a.x; v[1] = (_Float16)a.y; v[2] = (_Float16)a.z; v[3] = (_Float16)a.w;
        v[4] = (_Float16)b.x; v[5] = (_Float16)b.y; v[6] = (_Float16)b.z; v[7] = (_Float16)b.w;
        ((f16x8*)xh)[i] = v;
        return;
    }

    const float* W = (z == 0) ? W0 : (z == 1) ? W1 : (z == 2) ? W2 : W3;
    _Float16*    T = (z == 0) ? T0 : (z == 1) ? T1 : (z == 2) ? T2 : T3;

    const int nb = blockIdx.x * 64;
    const int kb = blockIdx.y * 64;
    const int tr = tid >> 4;
    const int tc = (tid & 15) << 2;

    #pragma unroll
    for (int rr = 0; rr < 4; ++rr) {
        const int k = kb + rr * 16 + tr;
        const float4 v = *(const float4*)&W[(size_t)k * DM + nb + tc];
        t[rr * 16 + tr][tc + 0] = v.x;
        t[rr * 16 + tr][tc + 1] = v.y;
        t[rr * 16 + tr][tc + 2] = v.z;
        t[rr * 16 + tr][tc + 3] = v.w;
    }
    __syncthreads();
    #pragma unroll
    for (int rr = 0; rr < 4; ++rr) {
        const int n = nb + rr * 16 + tr;
        f16x4 v;
        #pragma unroll
        for (int j = 0; j < 4; ++j)
            v[j] = (_Float16)t[tc + j][rr * 16 + tr];
        *(f16x4*)&T[(size_t)n * DM + kb + tc] = v;
    }
}

// ---------------------------------------------------------------------------
// Double-buffered MFMA GEMM over a single fused-N B^T matrix.
// Tile BM x BN (BM = WGR*WTR*16, BN = WGC*WTC*16), BK = 64, 4 waves.
// K-chunks XOR-swizzled in LDS: LDS[r][j] holds global chunk j^(r&7), so
// global_load_lds stays lane-contiguous AND ds_read_b128 is conflict-free
// (2-way only). One __syncthreads per K-tile; prefetch for tile k+1 issued
// right after the barrier overlaps the ds_read+MFMA of tile k.
// C is row-major with row stride CS (CS>DM => fused QKV output, 3-way bias).
template<int WGR, int WGC, int WTR, int WTC, bool F16OUT, int MINW, int CS>
__global__ __launch_bounds__(256, MINW) void gemm_db(
    const _Float16* __restrict__ A,
    const _Float16* __restrict__ Bt,
    const float* __restrict__ b0, const float* __restrict__ b1,
    const float* __restrict__ b2, void* __restrict__ C)
{
    constexpr int BM  = WGR * WTR * 16;
    constexpr int BN  = WGC * WTC * 16;
    constexpr int NA  = BM / 8;          // A chunks (8 rows x 64 k = 1 KB each)
    constexpr int NB  = BN / 8;          // B chunks
    constexpr int NC  = NA + NB;
    constexpr int CPW = NC / 4;          // chunks per wave
    static_assert(NC % 4 == 0);
    constexpr int BUF = (BM + BN) * 64;  // fp16 elements per buffer

    __shared__ _Float16 smem[2 * BUF];

    const int bn = blockIdx.x * BN;
    const int bm = blockIdx.y * BM;

    const int tid  = threadIdx.x;
    const int lane = tid & 63;
    const int wv   = tid >> 6;                    // 0..3
    const int wr   = (wv / WGC) * (WTR * 16);
    const int wc   = (wv % WGC) * (WTC * 16);
    const int lr   = lane & 15;
    const int lk   = lane >> 4;                   // 0..3
    const int rx   = lr & 7;

    // ---- staging setup: wave wv owns chunks [wv*CPW, wv*CPW+CPW) ----
    const _Float16* gsrc[CPW];
    int             loff[CPW];
    #pragma unroll
    for (int p = 0; p < CPW; ++p) {
        const int c   = wv * CPW + p;
        const int kch = ((lane & 7) ^ (lane >> 3)) << 3;   // swizzled k-offset
        if (c < NA) {
            const int rl = c * 8 + (lane >> 3);
            gsrc[p] = A + (size_t)(bm + rl) * DM + kch;
            loff[p] = c * 512 + lane * 8;
        } else {
            const int rl = (c - NA) * 8 + (lane >> 3);
            gsrc[p] = Bt + (size_t)(bn + rl) * DM + kch;
            loff[p] = BM * 64 + (c - NA) * 512 + lane * 8;
        }
    }

    // ---- fragment LDS offsets (element units, within a buffer) ----
    int offA[WTR][2], offB[WTC][2];
    #pragma unroll
    for (int ks = 0; ks < 2; ++ks) {
        const int sw = (((ks << 2) | lk) ^ rx) << 3;
        #pragma unroll
        for (int i = 0; i < WTR; ++i)
            offA[i][ks] = (wr + i * 16 + lr) * 64 + sw;
        #pragma unroll
        for (int j = 0; j < WTC; ++j)
            offB[j][ks] = BM * 64 + (wc + j * 16 + lr) * 64 + sw;
    }

    f32x4 acc[WTR][WTC] = {};

    auto prefetch = [&](int buf) {
        #pragma unroll
        for (int p = 0; p < CPW; ++p) {
            __builtin_amdgcn_global_load_lds(
                (const __attribute__((address_space(1))) void*)gsrc[p],
                (__attribute__((address_space(3))) void*)(smem + buf * BUF + loff[p]),
                16, 0, 0);
            gsrc[p] += 64;
        }
    };

    auto compute = [&](int buf) {
        const _Float16* base = smem + buf * BUF;
        #pragma unroll
        for (int ks = 0; ks < 2; ++ks) {
            f16x8 aF[WTR], bF[WTC];
            #pragma unroll
            for (int i = 0; i < WTR; ++i)
                aF[i] = *(const f16x8*)&base[offA[i][ks]];
            #pragma unroll
            for (int j = 0; j < WTC; ++j)
                bF[j] = *(const f16x8*)&base[offB[j][ks]];
            #pragma unroll
            for (int i = 0; i < WTR; ++i)
                #pragma unroll
                for (int j = 0; j < WTC; ++j)
                    acc[i][j] = __builtin_amdgcn_mfma_f32_16x16x32_f16(aF[i], bF[j], acc[i][j], 0, 0, 0);
        }
    };

    prefetch(0);                       // tile 0 -> buf0
    #pragma unroll 1
    for (int it2 = 0; it2 < 16; ++it2) {
        __syncthreads();               // buf0 writes done / buf1 reads done
        prefetch(1);                   // tile 2*it2+1 -> buf1 (flies over compute)
        compute(0);                    // tile 2*it2
        __syncthreads();               // buf1 writes done / buf0 reads done
        if (it2 < 15) prefetch(0);     // tile 2*it2+2 -> buf0
        compute(1);                    // tile 2*it2+1
    }

    // ---- epilogue: C/D layout col = lane&15, row = (lane>>4)*4 + reg ----
    #pragma unroll
    for (int i = 0; i < WTR; ++i) {
        #pragma unroll
        for (int j = 0; j < WTC; ++j) {
            const int col = bn + wc + j * 16 + lr;
            float bv;
            if constexpr (CS > DM) {   // fused QKV: 3-way bias select per lane
                const float* bp = (col < 2048) ? b0 : (col < 4096) ? b1 : b2;
                bv = bp[col & 2047];
            } else {
                bv = b0[col];
            }
            #pragma unroll
            for (int r = 0; r < 4; ++r) {
                const int row = bm + wr + i * 16 + lk * 4 + r;
                const float v = acc[i][j][r] + bv;
                if (F16OUT)
                    ((_Float16*)C)[(size_t)row * CS + col] = (_Float16)v;
                else
                    ((float*)C)[(size_t)row * CS + col] = v;
            }
        }
    }
}

// ---------------------------------------------------------------------------
// MFMA attention: one block per token, 4 waves, wave wv owns heads
// [64wv, 64wv+64). S^T = K.Q^T via mfma (K=8 zero-padded), exp2 in fp32
// (log2e folded into Q scale), pack to fp16 in LDS (wave-private region,
// no barrier), O = A.V via mfma.
// Q/K/V come interleaved per token: QKV[t][0:2048]=Q, [2048:4096]=K,
// [4096:6144]=V (fused-N GEMM output).
__global__ __launch_bounds__(256) void attn_mfma(
    const _Float16* __restrict__ QKV, _Float16* __restrict__ Oh)
{
    __shared__ _Float16 Vt[8][264];      // V transposed [d][g], padded
    __shared__ _Float16 Al[256][72];     // exp(S) [h][g-chunk 64], padded (36 KB)
    __shared__ _Float16 Ot[256][8];      // O bounce [h][d]

    const int t    = blockIdx.x;
    const int tid  = threadIdx.x;
    const int lane = tid & 63;
    const int wv   = tid >> 6;
    const int col  = lane & 15;
    const int quad = lane >> 4;
    const int hbase = wv * 64;

    const _Float16* qb = QKV + (size_t)t * (3 * DM);
    const _Float16* kb = qb + DM;
    const _Float16* vb = qb + 2 * DM;

    {
        const f16x8 v = *(const f16x8*)(vb + tid * 8);
        #pragma unroll
        for (int d = 0; d < 8; ++d) Vt[d][tid] = v[d];
    }

    f16x8 qf[4];
    #pragma unroll
    for (int ht = 0; ht < 4; ++ht) {
        f16x8 v = {};
        if (quad == 0)
            v = *(const f16x8*)(qb + (hbase + ht * 16 + col) * 8);
        #pragma unroll
        for (int j = 0; j < 8; ++j) qf[ht][j] = v[j] * (_Float16)(SCALE * LOG2E);
    }

    __syncthreads();   // Vt visible to all waves

    const f32x4 zf = {};
    float rsum[4] = {};
    f32x4 oacc[4] = {};

    #pragma unroll 1
    for (int c = 0; c < 4; ++c) {
        const int gchunk = c * 64;

        f16x8 kf[4];
        #pragma unroll
        for (int gt = 0; gt < 4; ++gt) {
            f16x8 v = {};
            if (quad == 0)
                v = *(const f16x8*)(kb + (gchunk + gt * 16 + col) * 8);
            kf[gt] = v;
        }

        f32x4 s[4][4];
        #pragma unroll
        for (int gt = 0; gt < 4; ++gt)
            #pragma unroll
            for (int ht = 0; ht < 4; ++ht)
                s[gt][ht] = __builtin_amdgcn_mfma_f32_16x16x32_f16(kf[gt], qf[ht], zf, 0, 0, 0);

        #pragma unroll
        for (int gt = 0; gt < 4; ++gt) {
            #pragma unroll
            for (int ht = 0; ht < 4; ++ht) {
                f16x4 e4;
                #pragma unroll
                for (int r = 0; r < 4; ++r) {
                    e4[r] = (_Float16)EXP2(s[gt][ht][r]);
                    rsum[ht] += (float)e4[r];
                }
                *(f16x4*)&Al[hbase + ht * 16 + col][gt * 16 + quad * 4] = e4;
            }
        }

        #pragma unroll
        for (int ks = 0; ks < 2; ++ks) {
            f16x8 vf = {};
            if (col < 8)
                vf = *(const f16x8*)&Vt[col][gchunk + ks * 32 + quad * 8];
            #pragma unroll
            for (int ht = 0; ht < 4; ++ht) {
                const f16x8 af = *(const f16x8*)&Al[hbase + ht * 16 + col][ks * 32 + quad * 8];
                oacc[ht] = __builtin_amdgcn_mfma_f32_16x16x32_f16(af, vf, oacc[ht], 0, 0, 0);
            }
        }
    }

    #pragma unroll
    for (int ht = 0; ht < 4; ++ht) {
        rsum[ht] += __shfl_xor(rsum[ht], 16, 64);
        rsum[ht] += __shfl_xor(rsum[ht], 32, 64);
    }

    #pragma unroll
    for (int ht = 0; ht < 4; ++ht) {
        #pragma unroll
        for (int r = 0; r < 4; ++r) {
            const float sh = __shfl(rsum[ht], quad * 4 + r, 64);
            const float v  = oacc[ht][r] / sh;
            if (col < 8)
                Ot[hbase + ht * 16 + quad * 4 + r][col] = (_Float16)v;
        }
    }
    const f16x8 ov = *(const f16x8*)&Ot[tid][0];
    *(f16x8*)(Oh + (size_t)t * DM + tid * 8) = ov;
}

// ---------------------------------------------------------------------------
extern "C" void kernel_launch(void* const* d_in, const int* in_sizes, int n_in,
                              void* d_out, int out_size, void* d_ws, size_t ws_size,
                              hipStream_t stream)
{
    const float* x  = (const float*)d_in[0];
    // d_in[1] = phase_shift: cancels analytically (cos^2 + sin^2 = 1), unused
    const float* Wq = (const float*)d_in[2];
    const float* bq = (const float*)d_in[3];
    const float* Wk = (const float*)d_in[4];
    const float* bk = (const float*)d_in[5];
    const float* Wv = (const float*)d_in[6];
    const float* bv = (const float*)d_in[7];
    const float* Wo = (const float*)d_in[8];
    const float* bo = (const float*)d_in[9];
    float* out = (float*)d_out;

    char* ws = (char*)d_ws;
    _Float16* xh  = (_Float16*)(ws);                 // 4 MB  [1024][2048]
    _Float16* Wt  = (_Float16*)(ws + (4u  << 20));   // 24 MB fused B^T [6144][2048] (q|k|v)
    _Float16* Wto = (_Float16*)(ws + (28u << 20));   // 8 MB
    _Float16* QKV = (_Float16*)(ws + (36u << 20));   // 12 MB [1024][6144] (q|k|v per token)
    _Float16* Oh  = (_Float16*)(ws + (48u << 20));   // 4 MB

    // cast x + cast/transpose 4 weights in one launch (q,k,v land contiguous)
    prep<<<dim3(32, 32, 5), dim3(256), 0, stream>>>(
        x, xh, Wq, Wk, Wv, Wo,
        Wt, Wt + 2048 * 2048, Wt + 2 * 2048 * 2048, Wto);

    // QKV as ONE fused-N GEMM: M=1024, N=6144, K=2048. Tile 128x96
    // (wave tile 64x48: 24 mfma / 14 ds_read = 1.71 density), dbuf 57 KB,
    // grid 64x8 = 512 blocks = exactly 2/CU, fully resident & balanced.
    gemm_db<2, 2, 4, 3, true, 2, 3 * DM><<<dim3(64, 8), dim3(256), 0, stream>>>(
        xh, Wt, bq, bk, bv, (void*)QKV);

    attn_mfma<<<dim3(M_TOK), dim3(256), 0, stream>>>(QKV, Oh);

    // output projection: 32x128 tiles, BK=64, dbuf. grid 16 x 32 = 512 blocks
    gemm_db<1, 4, 2, 2, false, 3, DM><<<dim3(16, 32), dim3(256), 0, stream>>>(
        Oh, Wto, bo, bo, bo, (void*)out);
}

// Round 2
// 191.733 us; speedup vs baseline: 1.0262x; 1.0262x over previous
//
#include <hip/hip_runtime.h>
#include <math.h>

#define M_TOK 1024   // B*S
#define DM    2048   // d_model
#define NH    256    // heads
#define HD    8      // head dim
#define SCALE 0.35355339059327373f   // 1/sqrt(8)
#define LOG2E 1.4426950408889634f

typedef _Float16 f16x8 __attribute__((ext_vector_type(8)));
typedef _Float16 f16x4 __attribute__((ext_vector_type(4)));
typedef float    f32x4 __attribute__((ext_vector_type(4)));

#if defined(__has_builtin)
#  if __has_builtin(__builtin_amdgcn_exp2f)
#    define EXP2(x) __builtin_amdgcn_exp2f(x)
#  endif
#endif
#ifndef EXP2
#  define EXP2(x) exp2f(x)
#endif

// counted vmcnt wait (asm immediate must be a literal -> constexpr dispatch)
template<int N>
__device__ __forceinline__ void vm_wait() {
    if constexpr (N == 0) asm volatile("s_waitcnt vmcnt(0)" ::: "memory");
    else if constexpr (N == 1) asm volatile("s_waitcnt vmcnt(1)" ::: "memory");
    else if constexpr (N == 2) asm volatile("s_waitcnt vmcnt(2)" ::: "memory");
    else if constexpr (N == 3) asm volatile("s_waitcnt vmcnt(3)" ::: "memory");
    else if constexpr (N == 4) asm volatile("s_waitcnt vmcnt(4)" ::: "memory");
    else if constexpr (N == 5) asm volatile("s_waitcnt vmcnt(5)" ::: "memory");
    else if constexpr (N == 6) asm volatile("s_waitcnt vmcnt(6)" ::: "memory");
    else if constexpr (N == 7) asm volatile("s_waitcnt vmcnt(7)" ::: "memory");
    else if constexpr (N == 8) asm volatile("s_waitcnt vmcnt(8)" ::: "memory");
    else static_assert(N <= 8, "add vmcnt case");
}

__device__ __forceinline__ void raw_barrier() {
    asm volatile("" ::: "memory");          // fence compiler memory motion
    __builtin_amdgcn_s_barrier();
    asm volatile("" ::: "memory");
}

// ---------------------------------------------------------------------------
// prep: z<4 -> weight fp32 [k][n] -> fp16 [n][k] (cast+transpose, 64x64 tiles);
//       z==4 -> x fp32 -> fp16 straight cast (8 elem/thread)
__global__ __launch_bounds__(256) void prep(
    const float* __restrict__ x, _Float16* __restrict__ xh,
    const float* __restrict__ W0, const float* __restrict__ W1,
    const float* __restrict__ W2, const float* __restrict__ W3,
    _Float16* __restrict__ T0, _Float16* __restrict__ T1,
    _Float16* __restrict__ T2, _Float16* __restrict__ T3)
{
    __shared__ float t[64][65];
    const int tid = threadIdx.x;
    const int z   = blockIdx.z;

    if (z == 4) {   // cast x
        const int i = (blockIdx.y * 32 + blockIdx.x) * 256 + tid;   // < 262144
        const float4 a = ((const float4*)x)[2 * i];
        const float4 b = ((const float4*)x)[2 * i + 1];
        f16x8 v;
        v[0] = (_Float16)a.x; v[1] = (_Float16)a.y; v[2] = (_Float16)a.z; v[3] = (_Float16)a.w;
        v[4] = (_Float16)b.x; v[5] = (_Float16)b.y; v[6] = (_Float16)b.z; v[7] = (_Float16)b.w;
        ((f16x8*)xh)[i] = v;
        return;
    }

    const float* W = (z == 0) ? W0 : (z == 1) ? W1 : (z == 2) ? W2 : W3;
    _Float16*    T = (z == 0) ? T0 : (z == 1) ? T1 : (z == 2) ? T2 : T3;

    const int nb = blockIdx.x * 64;
    const int kb = blockIdx.y * 64;
    const int tr = tid >> 4;
    const int tc = (tid & 15) << 2;

    #pragma unroll
    for (int rr = 0; rr < 4; ++rr) {
        const int k = kb + rr * 16 + tr;
        const float4 v = *(const float4*)&W[(size_t)k * DM + nb + tc];
        t[rr * 16 + tr][tc + 0] = v.x;
        t[rr * 16 + tr][tc + 1] = v.y;
        t[rr * 16 + tr][tc + 2] = v.z;
        t[rr * 16 + tr][tc + 3] = v.w;
    }
    __syncthreads();
    #pragma unroll
    for (int rr = 0; rr < 4; ++rr) {
        const int n = nb + rr * 16 + tr;
        f16x4 v;
        #pragma unroll
        for (int j = 0; j < 4; ++j)
            v[j] = (_Float16)t[tc + j][rr * 16 + tr];
        *(f16x4*)&T[(size_t)n * DM + kb + tc] = v;
    }
}

// ---------------------------------------------------------------------------
// Double-buffered MFMA GEMM, counted-vmcnt pipeline (T4) + setprio (T5).
// Tile BM x BN, BK = 64, 4 waves. K-chunks XOR-swizzled in LDS so
// global_load_lds stays lane-contiguous AND ds_read_b128 is conflict-free.
// Key change vs __syncthreads version: raw s_barrier + s_waitcnt vmcnt(CPW)
// -> next tile's CPW loads stay IN FLIGHT across the barrier (issued 2
// iterations ahead, ~2 compute phases of latency cover). Never drain to 0
// in the main loop (m218: counted-vs-drain0 = +38-73%).
// C row-major, row stride CS (CS>DM => fused QKV output, 3-way bias).
template<int WGR, int WGC, int WTR, int WTC, bool F16OUT, int MINW, int CS>
__global__ __launch_bounds__(256, MINW) void gemm_db(
    const _Float16* __restrict__ A,
    const _Float16* __restrict__ Bt,
    const float* __restrict__ b0, const float* __restrict__ b1,
    const float* __restrict__ b2, void* __restrict__ C)
{
    constexpr int BM  = WGR * WTR * 16;
    constexpr int BN  = WGC * WTC * 16;
    constexpr int NA  = BM / 8;          // A chunks (8 rows x 64 k = 1 KB each)
    constexpr int NB  = BN / 8;          // B chunks
    constexpr int NC  = NA + NB;
    constexpr int CPW = NC / 4;          // chunks per wave
    static_assert(NC % 4 == 0);
    constexpr int BUF = (BM + BN) * 64;  // fp16 elements per buffer

    __shared__ _Float16 smem[2 * BUF];

    const int bn = blockIdx.x * BN;
    const int bm = blockIdx.y * BM;

    const int tid  = threadIdx.x;
    const int lane = tid & 63;
    const int wv   = tid >> 6;                    // 0..3
    const int wr   = (wv / WGC) * (WTR * 16);
    const int wc   = (wv % WGC) * (WTC * 16);
    const int lr   = lane & 15;
    const int lk   = lane >> 4;                   // 0..3
    const int rx   = lr & 7;

    // ---- staging setup: wave wv owns chunks [wv*CPW, wv*CPW+CPW) ----
    const _Float16* gsrc[CPW];
    int             loff[CPW];
    #pragma unroll
    for (int p = 0; p < CPW; ++p) {
        const int c   = wv * CPW + p;
        const int kch = ((lane & 7) ^ (lane >> 3)) << 3;   // swizzled k-offset
        if (c < NA) {
            const int rl = c * 8 + (lane >> 3);
            gsrc[p] = A + (size_t)(bm + rl) * DM + kch;
            loff[p] = c * 512 + lane * 8;
        } else {
            const int rl = (c - NA) * 8 + (lane >> 3);
            gsrc[p] = Bt + (size_t)(bn + rl) * DM + kch;
            loff[p] = BM * 64 + (c - NA) * 512 + lane * 8;
        }
    }

    // ---- fragment LDS offsets (element units, within a buffer) ----
    int offA[WTR][2], offB[WTC][2];
    #pragma unroll
    for (int ks = 0; ks < 2; ++ks) {
        const int sw = (((ks << 2) | lk) ^ rx) << 3;
        #pragma unroll
        for (int i = 0; i < WTR; ++i)
            offA[i][ks] = (wr + i * 16 + lr) * 64 + sw;
        #pragma unroll
        for (int j = 0; j < WTC; ++j)
            offB[j][ks] = BM * 64 + (wc + j * 16 + lr) * 64 + sw;
    }

    f32x4 acc[WTR][WTC] = {};

    auto prefetch = [&](int buf) {
        #pragma unroll
        for (int p = 0; p < CPW; ++p) {
            __builtin_amdgcn_global_load_lds(
                (const __attribute__((address_space(1))) void*)gsrc[p],
                (__attribute__((address_space(3))) void*)(smem + buf * BUF + loff[p]),
                16, 0, 0);
            gsrc[p] += 64;
        }
    };

    auto compute = [&](int buf) {
        const _Float16* base = smem + buf * BUF;
        #pragma unroll
        for (int ks = 0; ks < 2; ++ks) {
            f16x8 aF[WTR], bF[WTC];
            #pragma unroll
            for (int i = 0; i < WTR; ++i)
                aF[i] = *(const f16x8*)&base[offA[i][ks]];
            #pragma unroll
            for (int j = 0; j < WTC; ++j)
                bF[j] = *(const f16x8*)&base[offB[j][ks]];
            __builtin_amdgcn_s_setprio(1);
            #pragma unroll
            for (int i = 0; i < WTR; ++i)
                #pragma unroll
                for (int j = 0; j < WTC; ++j)
                    acc[i][j] = __builtin_amdgcn_mfma_f32_16x16x32_f16(aF[i], bF[j], acc[i][j], 0, 0, 0);
            __builtin_amdgcn_s_setprio(0);
        }
    };

    // ---- counted-vmcnt double-buffer pipeline, depth 2 ----
    prefetch(0);                       // tile 0
    prefetch(1);                       // tile 1   (2*CPW in flight)
    #pragma unroll 1
    for (int t = 0; t < 32; ++t) {
        if (t < 31) vm_wait<CPW>();    // tile t landed; tile t+1 stays in flight
        else        vm_wait<0>();      // last tile: nothing younger to spare
        raw_barrier();                 // all waves' tile-t writes visible
        compute(t & 1);
        raw_barrier();                 // all waves done reading buf before overwrite
        if (t < 30) prefetch(t & 1);   // tile t+2 -> same buffer
    }

    // ---- epilogue: C/D layout col = lane&15, row = (lane>>4)*4 + reg ----
    #pragma unroll
    for (int i = 0; i < WTR; ++i) {
        #pragma unroll
        for (int j = 0; j < WTC; ++j) {
            const int col = bn + wc + j * 16 + lr;
            float bv;
            if constexpr (CS > DM) {   // fused QKV: 3-way bias select per lane
                const float* bp = (col < 2048) ? b0 : (col < 4096) ? b1 : b2;
                bv = bp[col & 2047];
            } else {
                bv = b0[col];
            }
            #pragma unroll
            for (int r = 0; r < 4; ++r) {
                const int row = bm + wr + i * 16 + lk * 4 + r;
                const float v = acc[i][j][r] + bv;
                if (F16OUT)
                    ((_Float16*)C)[(size_t)row * CS + col] = (_Float16)v;
                else
                    ((float*)C)[(size_t)row * CS + col] = v;
            }
        }
    }
}

// ---------------------------------------------------------------------------
// MFMA attention: 512 blocks x 2 tokens serial (2 blocks/CU at 45 KB LDS ->
// fully resident, no ragged second round). 4 waves, wave wv owns heads
// [64wv, 64wv+64). S^T = K.Q^T via mfma (K=8 zero-padded), exp2 in fp32
// (log2e folded into Q scale), pack to fp16 in LDS (wave-private region,
// no barrier), O = A.V via mfma.
// QKV interleaved per token: [t][0:2048]=Q, [2048:4096]=K, [4096:6144]=V.
__global__ __launch_bounds__(256) void attn_mfma(
    const _Float16* __restrict__ QKV, _Float16* __restrict__ Oh)
{
    __shared__ _Float16 Vt[8][264];      // V transposed [d][g], padded
    __shared__ _Float16 Al[256][72];     // exp(S) [h][g-chunk 64], padded (36 KB)
    __shared__ _Float16 Ot[256][8];      // O bounce [h][d]

    const int tid  = threadIdx.x;
    const int lane = tid & 63;
    const int wv   = tid >> 6;
    const int col  = lane & 15;
    const int quad = lane >> 4;
    const int hbase = wv * 64;

    #pragma unroll 1
    for (int tt = 0; tt < 2; ++tt) {
        const int t = blockIdx.x * 2 + tt;
        const _Float16* qb = QKV + (size_t)t * (3 * DM);
        const _Float16* kb = qb + DM;
        const _Float16* vb = qb + 2 * DM;

        __syncthreads();   // protect Vt overwrite vs previous token's readers

        {
            const f16x8 v = *(const f16x8*)(vb + tid * 8);
            #pragma unroll
            for (int d = 0; d < 8; ++d) Vt[d][tid] = v[d];
        }

        f16x8 qf[4];
        #pragma unroll
        for (int ht = 0; ht < 4; ++ht) {
            f16x8 v = {};
            if (quad == 0)
                v = *(const f16x8*)(qb + (hbase + ht * 16 + col) * 8);
            #pragma unroll
            for (int j = 0; j < 8; ++j) qf[ht][j] = v[j] * (_Float16)(SCALE * LOG2E);
        }

        __syncthreads();   // Vt visible to all waves

        const f32x4 zf = {};
        float rsum[4] = {};
        f32x4 oacc[4] = {};

        #pragma unroll 1
        for (int c = 0; c < 4; ++c) {
            const int gchunk = c * 64;

            f16x8 kf[4];
            #pragma unroll
            for (int gt = 0; gt < 4; ++gt) {
                f16x8 v = {};
                if (quad == 0)
                    v = *(const f16x8*)(kb + (gchunk + gt * 16 + col) * 8);
                kf[gt] = v;
            }

            f32x4 s[4][4];
            #pragma unroll
            for (int gt = 0; gt < 4; ++gt)
                #pragma unroll
                for (int ht = 0; ht < 4; ++ht)
                    s[gt][ht] = __builtin_amdgcn_mfma_f32_16x16x32_f16(kf[gt], qf[ht], zf, 0, 0, 0);

            #pragma unroll
            for (int gt = 0; gt < 4; ++gt) {
                #pragma unroll
                for (int ht = 0; ht < 4; ++ht) {
                    f16x4 e4;
                    #pragma unroll
                    for (int r = 0; r < 4; ++r) {
                        e4[r] = (_Float16)EXP2(s[gt][ht][r]);
                        rsum[ht] += (float)e4[r];
                    }
                    *(f16x4*)&Al[hbase + ht * 16 + col][gt * 16 + quad * 4] = e4;
                }
            }

            #pragma unroll
            for (int ks = 0; ks < 2; ++ks) {
                f16x8 vf = {};
                if (col < 8)
                    vf = *(const f16x8*)&Vt[col][gchunk + ks * 32 + quad * 8];
                #pragma unroll
                for (int ht = 0; ht < 4; ++ht) {
                    const f16x8 af = *(const f16x8*)&Al[hbase + ht * 16 + col][ks * 32 + quad * 8];
                    oacc[ht] = __builtin_amdgcn_mfma_f32_16x16x32_f16(af, vf, oacc[ht], 0, 0, 0);
                }
            }
        }

        #pragma unroll
        for (int ht = 0; ht < 4; ++ht) {
            rsum[ht] += __shfl_xor(rsum[ht], 16, 64);
            rsum[ht] += __shfl_xor(rsum[ht], 32, 64);
        }

        #pragma unroll
        for (int ht = 0; ht < 4; ++ht) {
            #pragma unroll
            for (int r = 0; r < 4; ++r) {
                const float sh = __shfl(rsum[ht], quad * 4 + r, 64);
                const float v  = oacc[ht][r] / sh;
                if (col < 8)
                    Ot[hbase + ht * 16 + quad * 4 + r][col] = (_Float16)v;
            }
        }
        const f16x8 ov = *(const f16x8*)&Ot[tid][0];   // same-wave rows: no barrier
        *(f16x8*)(Oh + (size_t)t * DM + tid * 8) = ov;
    }
}

// ---------------------------------------------------------------------------
extern "C" void kernel_launch(void* const* d_in, const int* in_sizes, int n_in,
                              void* d_out, int out_size, void* d_ws, size_t ws_size,
                              hipStream_t stream)
{
    const float* x  = (const float*)d_in[0];
    // d_in[1] = phase_shift: cancels analytically (cos^2 + sin^2 = 1), unused
    const float* Wq = (const float*)d_in[2];
    const float* bq = (const float*)d_in[3];
    const float* Wk = (const float*)d_in[4];
    const float* bk = (const float*)d_in[5];
    const float* Wv = (const float*)d_in[6];
    const float* bv = (const float*)d_in[7];
    const float* Wo = (const float*)d_in[8];
    const float* bo = (const float*)d_in[9];
    float* out = (float*)d_out;

    char* ws = (char*)d_ws;
    _Float16* xh  = (_Float16*)(ws);                 // 4 MB  [1024][2048]
    _Float16* Wt  = (_Float16*)(ws + (4u  << 20));   // 24 MB fused B^T [6144][2048] (q|k|v)
    _Float16* Wto = (_Float16*)(ws + (28u << 20));   // 8 MB
    _Float16* QKV = (_Float16*)(ws + (36u << 20));   // 12 MB [1024][6144] (q|k|v per token)
    _Float16* Oh  = (_Float16*)(ws + (48u << 20));   // 4 MB

    // cast x + cast/transpose 4 weights in one launch (q,k,v land contiguous)
    prep<<<dim3(32, 32, 5), dim3(256), 0, stream>>>(
        x, xh, Wq, Wk, Wv, Wo,
        Wt, Wt + 2048 * 2048, Wt + 2 * 2048 * 2048, Wto);

    // QKV as ONE fused-N GEMM: M=1024, N=6144, K=2048. Tile 128x96,
    // grid 64x8 = 512 blocks = exactly 2/CU. CPW=7 loads/wave/tile.
    gemm_db<2, 2, 4, 3, true, 2, 3 * DM><<<dim3(64, 8), dim3(256), 0, stream>>>(
        xh, Wt, bq, bk, bv, (void*)QKV);

    attn_mfma<<<dim3(M_TOK / 2), dim3(256), 0, stream>>>(QKV, Oh);

    // output projection: 32x128 tiles, grid 16x32 = 512 blocks. CPW=5.
    gemm_db<1, 4, 2, 2, false, 3, DM><<<dim3(16, 32), dim3(256), 0, stream>>>(
        Oh, Wto, bo, bo, bo, (void*)out);
}

// Round 3
// 185.248 us; speedup vs baseline: 1.0621x; 1.0350x over previous
//
#include <hip/hip_runtime.h>
#include <math.h>

#define M_TOK 1024   // B*S
#define DM    2048   // d_model
#define NH    256    // heads
#define HD    8      // head dim
#define SCALE 0.35355339059327373f   // 1/sqrt(8)
#define LOG2E 1.4426950408889634f

typedef _Float16 f16x8 __attribute__((ext_vector_type(8)));
typedef _Float16 f16x4 __attribute__((ext_vector_type(4)));
typedef float    f32x4 __attribute__((ext_vector_type(4)));

#if defined(__has_builtin)
#  if __has_builtin(__builtin_amdgcn_exp2f)
#    define EXP2(x) __builtin_amdgcn_exp2f(x)
#  endif
#endif
#ifndef EXP2
#  define EXP2(x) exp2f(x)
#endif

// counted vmcnt wait (asm immediate must be a literal -> constexpr dispatch)
template<int N>
__device__ __forceinline__ void vm_wait() {
    if constexpr (N == 0) asm volatile("s_waitcnt vmcnt(0)" ::: "memory");
    else if constexpr (N == 1) asm volatile("s_waitcnt vmcnt(1)" ::: "memory");
    else if constexpr (N == 2) asm volatile("s_waitcnt vmcnt(2)" ::: "memory");
    else if constexpr (N == 3) asm volatile("s_waitcnt vmcnt(3)" ::: "memory");
    else if constexpr (N == 4) asm volatile("s_waitcnt vmcnt(4)" ::: "memory");
    else if constexpr (N == 5) asm volatile("s_waitcnt vmcnt(5)" ::: "memory");
    else if constexpr (N == 6) asm volatile("s_waitcnt vmcnt(6)" ::: "memory");
    else if constexpr (N == 7) asm volatile("s_waitcnt vmcnt(7)" ::: "memory");
    else static_assert(N <= 7, "add vmcnt case");
}

__device__ __forceinline__ void raw_barrier() {
    asm volatile("" ::: "memory");          // fence compiler memory motion
    __builtin_amdgcn_s_barrier();
    asm volatile("" ::: "memory");
}

// ---------------------------------------------------------------------------
// prep: z<4 -> weight fp32 [k][n] -> fp16 [n][k] (cast+transpose, 64x64 tiles);
//       z==4 -> x fp32 -> fp16 straight cast (8 elem/thread)
__global__ __launch_bounds__(256) void prep(
    const float* __restrict__ x, _Float16* __restrict__ xh,
    const float* __restrict__ W0, const float* __restrict__ W1,
    const float* __restrict__ W2, const float* __restrict__ W3,
    _Float16* __restrict__ T0, _Float16* __restrict__ T1,
    _Float16* __restrict__ T2, _Float16* __restrict__ T3)
{
    __shared__ float t[64][65];
    const int tid = threadIdx.x;
    const int z   = blockIdx.z;

    if (z == 4) {   // cast x
        const int i = (blockIdx.y * 32 + blockIdx.x) * 256 + tid;   // < 262144
        const float4 a = ((const float4*)x)[2 * i];
        const float4 b = ((const float4*)x)[2 * i + 1];
        f16x8 v;
        v[0] = (_Float16)a.x; v[1] = (_Float16)a.y; v[2] = (_Float16)a.z; v[3] = (_Float16)a.w;
        v[4] = (_Float16)b.x; v[5] = (_Float16)b.y; v[6] = (_Float16)b.z; v[7] = (_Float16)b.w;
        ((f16x8*)xh)[i] = v;
        return;
    }

    const float* W = (z == 0) ? W0 : (z == 1) ? W1 : (z == 2) ? W2 : W3;
    _Float16*    T = (z == 0) ? T0 : (z == 1) ? T1 : (z == 2) ? T2 : T3;

    const int nb = blockIdx.x * 64;
    const int kb = blockIdx.y * 64;
    const int tr = tid >> 4;
    const int tc = (tid & 15) << 2;

    #pragma unroll
    for (int rr = 0; rr < 4; ++rr) {
        const int k = kb + rr * 16 + tr;
        const float4 v = *(const float4*)&W[(size_t)k * DM + nb + tc];
        t[rr * 16 + tr][tc + 0] = v.x;
        t[rr * 16 + tr][tc + 1] = v.y;
        t[rr * 16 + tr][tc + 2] = v.z;
        t[rr * 16 + tr][tc + 3] = v.w;
    }
    __syncthreads();
    #pragma unroll
    for (int rr = 0; rr < 4; ++rr) {
        const int n = nb + rr * 16 + tr;
        f16x4 v;
        #pragma unroll
        for (int j = 0; j < 4; ++j)
            v[j] = (_Float16)t[tc + j][rr * 16 + tr];
        *(f16x4*)&T[(size_t)n * DM + kb + tc] = v;
    }
}

// ---------------------------------------------------------------------------
// Triple-buffered MFMA GEMM, prefetch distance 2 (T3/T4/T5 combined).
// 512 threads / 8 waves (WGR x WGC), tile BM x BN, BK = 64, K = 2048 (32 tiles).
// Pipeline: loads for tile t issued during tile t-2 -> ~2 compute phases of
// latency cover; vm_wait<CPW> at tile start leaves tile t+1's loads in flight
// (never drains to 0 in the loop). 3 LDS buffers rotate (unroll-by-3 makes
// all buffer bases compile-time). One barrier per tile (+ optional mid-phase
// barrier for fat tiles: stage/ds_read/MFMA interleave, m196 lever).
// K-chunks XOR-swizzled in LDS: global_load_lds lane-contiguous AND
// ds_read_b128 conflict-free. C row-major, row stride CS (CS>DM => fused
// QKV output with 3-way bias select).
template<int WGR, int WGC, int WTR, int WTC, bool F16OUT, int CS, bool SPLIT>
__global__ __launch_bounds__(512, 2) void gemm_p3(
    const _Float16* __restrict__ A,
    const _Float16* __restrict__ Bt,
    const float* __restrict__ b0, const float* __restrict__ b1,
    const float* __restrict__ b2, void* __restrict__ C)
{
    constexpr int NW  = WGR * WGC;
    static_assert(NW == 8, "8 waves");
    constexpr int BM  = WGR * WTR * 16;
    constexpr int BN  = WGC * WTC * 16;
    constexpr int NA  = BM / 8;          // A chunks (8 rows x 64 k = 1 KB each)
    constexpr int NB  = BN / 8;          // B chunks
    constexpr int NC  = NA + NB;
    constexpr int CPW = NC / NW;         // chunks per wave per tile
    static_assert(NC % NW == 0);
    constexpr int S0  = (CPW + 1) / 2;   // stage split point
    constexpr int BUF = (BM + BN) * 64;  // fp16 elements per buffer
    constexpr int KT  = 32;              // K tiles (2048 / 64)
    static_assert((KT - 2) % 3 == 0 || true);

    __shared__ _Float16 smem[3 * BUF];

    const int bn = blockIdx.x * BN;
    const int bm = blockIdx.y * BM;

    const int tid  = threadIdx.x;
    const int lane = tid & 63;
    const int wv   = tid >> 6;                    // 0..7
    const int wr   = (wv / WGC) * (WTR * 16);
    const int wc   = (wv % WGC) * (WTC * 16);
    const int lr   = lane & 15;
    const int lk   = lane >> 4;                   // 0..3
    const int rx   = lr & 7;

    // ---- staging setup: wave wv owns chunks [wv*CPW, wv*CPW+CPW) ----
    const _Float16* gsrc[CPW];
    int             loff[CPW];
    #pragma unroll
    for (int p = 0; p < CPW; ++p) {
        const int c   = wv * CPW + p;
        const int kch = ((lane & 7) ^ (lane >> 3)) << 3;   // swizzled k-offset
        if (c < NA) {
            const int rl = c * 8 + (lane >> 3);
            gsrc[p] = A + (size_t)(bm + rl) * DM + kch;
            loff[p] = c * 512 + lane * 8;
        } else {
            const int rl = (c - NA) * 8 + (lane >> 3);
            gsrc[p] = Bt + (size_t)(bn + rl) * DM + kch;
            loff[p] = BM * 64 + (c - NA) * 512 + lane * 8;
        }
    }

    // ---- fragment LDS offsets (element units, within a buffer) ----
    int offA[WTR][2], offB[WTC][2];
    #pragma unroll
    for (int ks = 0; ks < 2; ++ks) {
        const int sw = (((ks << 2) | lk) ^ rx) << 3;
        #pragma unroll
        for (int i = 0; i < WTR; ++i)
            offA[i][ks] = (wr + i * 16 + lr) * 64 + sw;
        #pragma unroll
        for (int j = 0; j < WTC; ++j)
            offB[j][ks] = BM * 64 + (wc + j * 16 + lr) * 64 + sw;
    }

    f32x4 acc[WTR][WTC] = {};

    // issue chunks [from,to) of the next-next tile into LDS buffer buf
    auto stage = [&](int buf, int from, int to) {
        #pragma unroll
        for (int p = 0; p < CPW; ++p) {
            if (p >= from && p < to) {
                __builtin_amdgcn_global_load_lds(
                    (const __attribute__((address_space(1))) void*)gsrc[p],
                    (__attribute__((address_space(3))) void*)(smem + buf * BUF + loff[p]),
                    16, 0, 0);
                gsrc[p] += 64;
            }
        }
    };

    // one ks half-tile: 	ds_read fragments + MFMA cluster
    auto cphase = [&](int buf, int ks) {
        const _Float16* base = smem + buf * BUF;
        f16x8 aF[WTR], bF[WTC];
        #pragma unroll
        for (int i = 0; i < WTR; ++i)
            aF[i] = *(const f16x8*)&base[offA[i][ks]];
        #pragma unroll
        for (int j = 0; j < WTC; ++j)
            bF[j] = *(const f16x8*)&base[offB[j][ks]];
        __builtin_amdgcn_s_setprio(1);
        #pragma unroll
        for (int i = 0; i < WTR; ++i)
            #pragma unroll
            for (int j = 0; j < WTC; ++j)
                acc[i][j] = __builtin_amdgcn_mfma_f32_16x16x32_f16(aF[i], bF[j], acc[i][j], 0, 0, 0);
        __builtin_amdgcn_s_setprio(0);
    };

    // per-tile body. buf is a literal at every call site (constant-folded).
    // do_stage: issue tile t+2's loads into buffer (buf+2)%3.
    auto tile = [&](int buf, bool do_stage, bool last) {
        if (last) vm_wait<0>();        // final tile: nothing younger in flight
        else      vm_wait<CPW>();      // tile t landed; t+1's CPW stay in flight
        raw_barrier();                 // all waves' tile-t chunks visible
        const int nb3 = (buf + 2 >= 3) ? buf - 1 : buf + 2;
        if (do_stage) stage(nb3, 0, S0);
        cphase(buf, 0);
        if (SPLIT) raw_barrier();      // phase split: keeps stage/read/MFMA interleaved
        if (do_stage) stage(nb3, S0, CPW);
        cphase(buf, 1);
        raw_barrier();                 // tile-t reads done before t+3 could overwrite
    };

    // ---- pipeline: prologue 2 tiles deep, then rotate 3 buffers ----
    stage(0, 0, CPW);                  // tile 0 -> buf 0
    stage(1, 0, CPW);                  // tile 1 -> buf 1
    #pragma unroll 1
    for (int tt = 0; tt < KT - 2; tt += 3) {
        tile(0, true, false);
        tile(1, true, false);
        tile(2, true, false);
    }
    tile(0, false, false);             // tile 30 (no further staging)
    tile(1, false, true);              // tile 31 (drain)

    // ---- epilogue: C/D layout col = lane&15, row = (lane>>4)*4 + reg ----
    #pragma unroll
    for (int i = 0; i < WTR; ++i) {
        #pragma unroll
        for (int j = 0; j < WTC; ++j) {
            const int col = bn + wc + j * 16 + lr;
            float bv;
            if constexpr (CS > DM) {   // fused QKV: 3-way bias select per lane
                const float* bp = (col < 2048) ? b0 : (col < 4096) ? b1 : b2;
                bv = bp[col & 2047];
            } else {
                bv = b0[col];
            }
            #pragma unroll
            for (int r = 0; r < 4; ++r) {
                const int row = bm + wr + i * 16 + lk * 4 + r;
                const float v = acc[i][j][r] + bv;
                if (F16OUT)
                    ((_Float16*)C)[(size_t)row * CS + col] = (_Float16)v;
                else
                    ((float*)C)[(size_t)row * CS + col] = v;
            }
        }
    }
}

// ---------------------------------------------------------------------------
// MFMA attention: 512 blocks x 2 tokens serial (2 blocks/CU at 45 KB LDS ->
// fully resident, no ragged second round). 4 waves, wave wv owns heads
// [64wv, 64wv+64). S^T = K.Q^T via mfma (K=8 zero-padded), exp2 in fp32
// (log2e folded into Q scale), pack to fp16 in LDS (wave-private region,
// no barrier), O = A.V via mfma.
// QKV interleaved per token: [t][0:2048]=Q, [2048:4096]=K, [4096:6144]=V.
__global__ __launch_bounds__(256) void attn_mfma(
    const _Float16* __restrict__ QKV, _Float16* __restrict__ Oh)
{
    __shared__ _Float16 Vt[8][264];      // V transposed [d][g], padded
    __shared__ _Float16 Al[256][72];     // exp(S) [h][g-chunk 64], padded (36 KB)
    __shared__ _Float16 Ot[256][8];      // O bounce [h][d]

    const int tid  = threadIdx.x;
    const int lane = tid & 63;
    const int wv   = tid >> 6;
    const int col  = lane & 15;
    const int quad = lane >> 4;
    const int hbase = wv * 64;

    #pragma unroll 1
    for (int tt = 0; tt < 2; ++tt) {
        const int t = blockIdx.x * 2 + tt;
        const _Float16* qb = QKV + (size_t)t * (3 * DM);
        const _Float16* kb = qb + DM;
        const _Float16* vb = qb + 2 * DM;

        __syncthreads();   // protect Vt overwrite vs previous token's readers

        {
            const f16x8 v = *(const f16x8*)(vb + tid * 8);
            #pragma unroll
            for (int d = 0; d < 8; ++d) Vt[d][tid] = v[d];
        }

        f16x8 qf[4];
        #pragma unroll
        for (int ht = 0; ht < 4; ++ht) {
            f16x8 v = {};
            if (quad == 0)
                v = *(const f16x8*)(qb + (hbase + ht * 16 + col) * 8);
            #pragma unroll
            for (int j = 0; j < 8; ++j) qf[ht][j] = v[j] * (_Float16)(SCALE * LOG2E);
        }

        __syncthreads();   // Vt visible to all waves

        const f32x4 zf = {};
        float rsum[4] = {};
        f32x4 oacc[4] = {};

        #pragma unroll 1
        for (int c = 0; c < 4; ++c) {
            const int gchunk = c * 64;

            f16x8 kf[4];
            #pragma unroll
            for (int gt = 0; gt < 4; ++gt) {
                f16x8 v = {};
                if (quad == 0)
                    v = *(const f16x8*)(kb + (gchunk + gt * 16 + col) * 8);
                kf[gt] = v;
            }

            f32x4 s[4][4];
            #pragma unroll
            for (int gt = 0; gt < 4; ++gt)
                #pragma unroll
                for (int ht = 0; ht < 4; ++ht)
                    s[gt][ht] = __builtin_amdgcn_mfma_f32_16x16x32_f16(kf[gt], qf[ht], zf, 0, 0, 0);

            #pragma unroll
            for (int gt = 0; gt < 4; ++gt) {
                #pragma unroll
                for (int ht = 0; ht < 4; ++ht) {
                    f16x4 e4;
                    #pragma unroll
                    for (int r = 0; r < 4; ++r) {
                        e4[r] = (_Float16)EXP2(s[gt][ht][r]);
                        rsum[ht] += (float)e4[r];
                    }
                    *(f16x4*)&Al[hbase + ht * 16 + col][gt * 16 + quad * 4] = e4;
                }
            }

            #pragma unroll
            for (int ks = 0; ks < 2; ++ks) {
                f16x8 vf = {};
                if (col < 8)
                    vf = *(const f16x8*)&Vt[col][gchunk + ks * 32 + quad * 8];
                #pragma unroll
                for (int ht = 0; ht < 4; ++ht) {
                    const f16x8 af = *(const f16x8*)&Al[hbase + ht * 16 + col][ks * 32 + quad * 8];
                    oacc[ht] = __builtin_amdgcn_mfma_f32_16x16x32_f16(af, vf, oacc[ht], 0, 0, 0);
                }
            }
        }

        #pragma unroll
        for (int ht = 0; ht < 4; ++ht) {
            rsum[ht] += __shfl_xor(rsum[ht], 16, 64);
            rsum[ht] += __shfl_xor(rsum[ht], 32, 64);
        }

        #pragma unroll
        for (int ht = 0; ht < 4; ++ht) {
            #pragma unroll
            for (int r = 0; r < 4; ++r) {
                const float sh = __shfl(rsum[ht], quad * 4 + r, 64);
                const float v  = oacc[ht][r] / sh;
                if (col < 8)
                    Ot[hbase + ht * 16 + quad * 4 + r][col] = (_Float16)v;
            }
        }
        const f16x8 ov = *(const f16x8*)&Ot[tid][0];   // same-wave rows: no barrier
        *(f16x8*)(Oh + (size_t)t * DM + tid * 8) = ov;
    }
}

// ---------------------------------------------------------------------------
extern "C" void kernel_launch(void* const* d_in, const int* in_sizes, int n_in,
                              void* d_out, int out_size, void* d_ws, size_t ws_size,
                              hipStream_t stream)
{
    const float* x  = (const float*)d_in[0];
    // d_in[1] = phase_shift: cancels analytically (cos^2 + sin^2 = 1), unused
    const float* Wq = (const float*)d_in[2];
    const float* bq = (const float*)d_in[3];
    const float* Wk = (const float*)d_in[4];
    const float* bk = (const float*)d_in[5];
    const float* Wv = (const float*)d_in[6];
    const float* bv = (const float*)d_in[7];
    const float* Wo = (const float*)d_in[8];
    const float* bo = (const float*)d_in[9];
    float* out = (float*)d_out;

    char* ws = (char*)d_ws;
    _Float16* xh  = (_Float16*)(ws);                 // 4 MB  [1024][2048]
    _Float16* Wt  = (_Float16*)(ws + (4u  << 20));   // 24 MB fused B^T [6144][2048] (q|k|v)
    _Float16* Wto = (_Float16*)(ws + (28u << 20));   // 8 MB
    _Float16* QKV = (_Float16*)(ws + (36u << 20));   // 12 MB [1024][6144] (q|k|v per token)
    _Float16* Oh  = (_Float16*)(ws + (48u << 20));   // 4 MB

    // cast x + cast/transpose 4 weights in one launch (q,k,v land contiguous)
    prep<<<dim3(32, 32, 5), dim3(256), 0, stream>>>(
        x, xh, Wq, Wk, Wv, Wo,
        Wt, Wt + 2048 * 2048, Wt + 2 * 2048 * 2048, Wto);

    // QKV as ONE fused-N GEMM: M=1024, N=6144, K=2048. Tile 128x192,
    // 8 waves (wave tile 64x48, density 1.71), 3 LDS buffers (120 KB),
    // prefetch distance 2. Grid 32x8 = 256 blocks = exactly 1/CU.
    gemm_p3<2, 4, 4, 3, true, 3 * DM, true><<<dim3(32, 8), dim3(512), 0, stream>>>(
        xh, Wt, bq, bk, bv, (void*)QKV);

    attn_mfma<<<dim3(M_TOK / 2), dim3(256), 0, stream>>>(QKV, Oh);

    // output projection: M=1024, N=2048, K=2048. Tile 64x128, 8 waves
    // (wave tile 32x32), 3 buffers (72 KB), prefetch distance 2.
    // Grid 16x16 = 256 blocks = exactly 1/CU.
    gemm_p3<2, 4, 2, 2, false, DM, false><<<dim3(16, 16), dim3(512), 0, stream>>>(
        Oh, Wto, bo, bo, bo, (void*)out);
}

// Round 4
// 183.714 us; speedup vs baseline: 1.0710x; 1.0083x over previous
//
#include <hip/hip_runtime.h>
#include <math.h>

#define M_TOK 1024   // B*S
#define DM    2048   // d_model
#define NH    256    // heads
#define HD    8      // head dim
#define SCALE 0.35355339059327373f   // 1/sqrt(8)
#define LOG2E 1.4426950408889634f

typedef _Float16 f16x8 __attribute__((ext_vector_type(8)));
typedef _Float16 f16x4 __attribute__((ext_vector_type(4)));
typedef float    f32x4 __attribute__((ext_vector_type(4)));

#if defined(__has_builtin)
#  if __has_builtin(__builtin_amdgcn_exp2f)
#    define EXP2(x) __builtin_amdgcn_exp2f(x)
#  endif
#endif
#ifndef EXP2
#  define EXP2(x) exp2f(x)
#endif

// counted vmcnt wait (asm immediate must be a literal -> constexpr dispatch)
template<int N>
__device__ __forceinline__ void vm_wait() {
    if constexpr (N == 0) asm volatile("s_waitcnt vmcnt(0)" ::: "memory");
    else if constexpr (N == 1) asm volatile("s_waitcnt vmcnt(1)" ::: "memory");
    else if constexpr (N == 2) asm volatile("s_waitcnt vmcnt(2)" ::: "memory");
    else if constexpr (N == 3) asm volatile("s_waitcnt vmcnt(3)" ::: "memory");
    else if constexpr (N == 4) asm volatile("s_waitcnt vmcnt(4)" ::: "memory");
    else if constexpr (N == 5) asm volatile("s_waitcnt vmcnt(5)" ::: "memory");
    else if constexpr (N == 6) asm volatile("s_waitcnt vmcnt(6)" ::: "memory");
    else if constexpr (N == 7) asm volatile("s_waitcnt vmcnt(7)" ::: "memory");
    else if constexpr (N == 8) asm volatile("s_waitcnt vmcnt(8)" ::: "memory");
    else static_assert(N <= 8, "add vmcnt case");
}

__device__ __forceinline__ void raw_barrier() {
    asm volatile("" ::: "memory");          // fence compiler memory motion
    __builtin_amdgcn_s_barrier();
    asm volatile("" ::: "memory");
}

// ---------------------------------------------------------------------------
// prep: z<4 -> weight fp32 [k][n] -> fp16 [n][k] (cast+transpose, 64x64 tiles);
//       z==4 -> x fp32 -> fp16 straight cast (8 elem/thread)
__global__ __launch_bounds__(256) void prep(
    const float* __restrict__ x, _Float16* __restrict__ xh,
    const float* __restrict__ W0, const float* __restrict__ W1,
    const float* __restrict__ W2, const float* __restrict__ W3,
    _Float16* __restrict__ T0, _Float16* __restrict__ T1,
    _Float16* __restrict__ T2, _Float16* __restrict__ T3)
{
    __shared__ float t[64][65];
    const int tid = threadIdx.x;
    const int z   = blockIdx.z;

    if (z == 4) {   // cast x
        const int i = (blockIdx.y * 32 + blockIdx.x) * 256 + tid;   // < 262144
        const float4 a = ((const float4*)x)[2 * i];
        const float4 b = ((const float4*)x)[2 * i + 1];
        f16x8 v;
        v[0] = (_Float16)a.x; v[1] = (_Float16)a.y; v[2] = (_Float16)a.z; v[3] = (_Float16)a.w;
        v[4] = (_Float16)b.x; v[5] = (_Float16)b.y; v[6] = (_Float16)b.z; v[7] = (_Float16)b.w;
        ((f16x8*)xh)[i] = v;
        return;
    }

    const float* W = (z == 0) ? W0 : (z == 1) ? W1 : (z == 2) ? W2 : W3;
    _Float16*    T = (z == 0) ? T0 : (z == 1) ? T1 : (z == 2) ? T2 : T3;

    const int nb = blockIdx.x * 64;
    const int kb = blockIdx.y * 64;
    const int tr = tid >> 4;
    const int tc = (tid & 15) << 2;

    #pragma unroll
    for (int rr = 0; rr < 4; ++rr) {
        const int k = kb + rr * 16 + tr;
        const float4 v = *(const float4*)&W[(size_t)k * DM + nb + tc];
        t[rr * 16 + tr][tc + 0] = v.x;
        t[rr * 16 + tr][tc + 1] = v.y;
        t[rr * 16 + tr][tc + 2] = v.z;
        t[rr * 16 + tr][tc + 3] = v.w;
    }
    __syncthreads();
    #pragma unroll
    for (int rr = 0; rr < 4; ++rr) {
        const int n = nb + rr * 16 + tr;
        f16x4 v;
        #pragma unroll
        for (int j = 0; j < 4; ++j)
            v[j] = (_Float16)t[tc + j][rr * 16 + tr];
        *(f16x4*)&T[(size_t)n * DM + kb + tc] = v;
    }
}

// ---------------------------------------------------------------------------
// Multi-buffered MFMA GEMM, prefetch distance NBUF-1 (T3/T4/T5 combined).
// 512 threads / 8 waves (WGR x WGC), tile BM x BN, BK = 64, K = 2048 (32 tiles).
// Pipeline: loads for tile t issued during tile t-(NBUF-1); vm_wait<(D-1)*CPW>
// at tile start leaves the younger tiles' loads in flight (never drains to 0
// in the main loop). NBUF LDS buffers rotate; all buffer indices literal at
// call sites. Per-phase order: {ds_read frags -> stage next tile -> MFMA}
// (m201 order: gload issue hides under ds_read latency, MFMA gated only by
// its reads). K-chunks XOR-swizzled in LDS: global_load_lds lane-contiguous
// AND ds_read_b128 conflict-free. C row-major, row stride CS (CS>DM => fused
// QKV output with 3-way bias select).
template<int WGR, int WGC, int WTR, int WTC, bool F16OUT, int CS, bool SPLIT, int NBUF>
__global__ __launch_bounds__(512, 2) void gemm_p3(
    const _Float16* __restrict__ A,
    const _Float16* __restrict__ Bt,
    const float* __restrict__ b0, const float* __restrict__ b1,
    const float* __restrict__ b2, void* __restrict__ C)
{
    constexpr int NW  = WGR * WGC;
    static_assert(NW == 8, "8 waves");
    constexpr int D   = NBUF - 1;        // prefetch depth
    constexpr int BM  = WGR * WTR * 16;
    constexpr int BN  = WGC * WTC * 16;
    constexpr int NA  = BM / 8;          // A chunks (8 rows x 64 k = 1 KB each)
    constexpr int NB  = BN / 8;          // B chunks
    constexpr int NC  = NA + NB;
    constexpr int CPW = NC / NW;         // chunks per wave per tile
    static_assert(NC % NW == 0);
    constexpr int S0  = (CPW + 1) / 2;   // stage split point
    constexpr int BUF = (BM + BN) * 64;  // fp16 elements per buffer
    constexpr int KT  = 32;              // K tiles (2048 / 64)
    constexpr int WMAIN = (D - 1) * CPW; // steady-state vmcnt

    __shared__ _Float16 smem[NBUF * BUF];

    const int bn = blockIdx.x * BN;
    const int bm = blockIdx.y * BM;

    const int tid  = threadIdx.x;
    const int lane = tid & 63;
    const int wv   = tid >> 6;                    // 0..7
    const int wr   = (wv / WGC) * (WTR * 16);
    const int wc   = (wv % WGC) * (WTC * 16);
    const int lr   = lane & 15;
    const int lk   = lane >> 4;                   // 0..3
    const int rx   = lr & 7;

    // ---- staging setup: wave wv owns chunks [wv*CPW, wv*CPW+CPW) ----
    const _Float16* gsrc[CPW];
    int             loff[CPW];
    #pragma unroll
    for (int p = 0; p < CPW; ++p) {
        const int c   = wv * CPW + p;
        const int kch = ((lane & 7) ^ (lane >> 3)) << 3;   // swizzled k-offset
        if (c < NA) {
            const int rl = c * 8 + (lane >> 3);
            gsrc[p] = A + (size_t)(bm + rl) * DM + kch;
            loff[p] = c * 512 + lane * 8;
        } else {
            const int rl = (c - NA) * 8 + (lane >> 3);
            gsrc[p] = Bt + (size_t)(bn + rl) * DM + kch;
            loff[p] = BM * 64 + (c - NA) * 512 + lane * 8;
        }
    }

    // ---- fragment LDS offsets (element units, within a buffer) ----
    int offA[WTR][2], offB[WTC][2];
    #pragma unroll
    for (int ks = 0; ks < 2; ++ks) {
        const int sw = (((ks << 2) | lk) ^ rx) << 3;
        #pragma unroll
        for (int i = 0; i < WTR; ++i)
            offA[i][ks] = (wr + i * 16 + lr) * 64 + sw;
        #pragma unroll
        for (int j = 0; j < WTC; ++j)
            offB[j][ks] = BM * 64 + (wc + j * 16 + lr) * 64 + sw;
    }

    f32x4 acc[WTR][WTC] = {};

    // issue chunks [from,to) of a future tile into LDS buffer sbuf
    auto stage = [&](int sbuf, int from, int to) {
        #pragma unroll
        for (int p = 0; p < CPW; ++p) {
            if (p >= from && p < to) {
                __builtin_amdgcn_global_load_lds(
                    (const __attribute__((address_space(1))) void*)gsrc[p],
                    (__attribute__((address_space(3))) void*)(smem + sbuf * BUF + loff[p]),
                    16, 0, 0);
                gsrc[p] += 64;
            }
        }
    };

    // one ks half-tile: ds_read frags -> stage -> MFMA cluster
    auto phase = [&](int buf, int ks, int sbuf, int from, int to, bool do_stage) {
        const _Float16* base = smem + buf * BUF;
        f16x8 aF[WTR], bF[WTC];
        #pragma unroll
        for (int i = 0; i < WTR; ++i)
            aF[i] = *(const f16x8*)&base[offA[i][ks]];
        #pragma unroll
        for (int j = 0; j < WTC; ++j)
            bF[j] = *(const f16x8*)&base[offB[j][ks]];
        if (do_stage) stage(sbuf, from, to);
        __builtin_amdgcn_s_setprio(1);
        #pragma unroll
        for (int i = 0; i < WTR; ++i)
            #pragma unroll
            for (int j = 0; j < WTC; ++j)
                acc[i][j] = __builtin_amdgcn_mfma_f32_16x16x32_f16(aF[i], bF[j], acc[i][j], 0, 0, 0);
        __builtin_amdgcn_s_setprio(0);
    };

    // per-tile body; caller does vm_wait first. sbuf = buffer for tile t+D.
    auto tile = [&](int buf, int sbuf, bool do_stage) {
        raw_barrier();                 // all waves' tile-t chunks visible
        phase(buf, 0, sbuf, 0, S0, do_stage);
        if (SPLIT) raw_barrier();      // phase split: stage/read/MFMA interleave
        phase(buf, 1, sbuf, S0, CPW, do_stage);
        raw_barrier();                 // tile-t reads done before buf reuse
    };

    // ---- pipeline: prologue D tiles deep, rotate NBUF buffers ----
    if constexpr (NBUF == 3) {
        stage(0, 0, CPW); stage(1, 0, CPW);
        #pragma unroll 1
        for (int tt = 0; tt < KT - 2; tt += 3) {
            vm_wait<WMAIN>(); tile(0, 2, true);
            vm_wait<WMAIN>(); tile(1, 0, true);
            vm_wait<WMAIN>(); tile(2, 1, true);
        }
        vm_wait<WMAIN>(); tile(0, 0, false);   // tile 30
        vm_wait<0>();     tile(1, 0, false);   // tile 31 (drain)
    } else {
        static_assert(NBUF == 4);
        stage(0, 0, CPW); stage(1, 0, CPW); stage(2, 0, CPW);
        #pragma unroll 1
        for (int tt = 0; tt < KT - 4; tt += 4) {   // tiles 0..27
            vm_wait<WMAIN>(); tile(0, 3, true);
            vm_wait<WMAIN>(); tile(1, 0, true);
            vm_wait<WMAIN>(); tile(2, 1, true);
            vm_wait<WMAIN>(); tile(3, 2, true);
        }
        vm_wait<WMAIN>(); tile(0, 3, true);    // tile 28 (stages tile 31)
        vm_wait<WMAIN>(); tile(1, 0, false);   // tile 29
        vm_wait<CPW>();   tile(2, 0, false);   // tile 30
        vm_wait<0>();     tile(3, 0, false);   // tile 31 (drain)
    }

    // ---- epilogue: C/D layout col = lane&15, row = (lane>>4)*4 + reg ----
    #pragma unroll
    for (int i = 0; i < WTR; ++i) {
        #pragma unroll
        for (int j = 0; j < WTC; ++j) {
            const int col = bn + wc + j * 16 + lr;
            float bv;
            if constexpr (CS > DM) {   // fused QKV: 3-way bias select per lane
                const float* bp = (col < 2048) ? b0 : (col < 4096) ? b1 : b2;
                bv = bp[col & 2047];
            } else {
                bv = b0[col];
            }
            #pragma unroll
            for (int r = 0; r < 4; ++r) {
                const int row = bm + wr + i * 16 + lk * 4 + r;
                const float v = acc[i][j][r] + bv;
                if (F16OUT)
                    ((_Float16*)C)[(size_t)row * CS + col] = (_Float16)v;
                else
                    ((float*)C)[(size_t)row * CS + col] = v;
            }
        }
    }
}

// ---------------------------------------------------------------------------
// MFMA attention: 512 blocks x 2 tokens serial (2 blocks/CU at 45 KB LDS ->
// fully resident, no ragged second round). 4 waves, wave wv owns heads
// [64wv, 64wv+64). S^T = K.Q^T via mfma (K=8 zero-padded), exp2 in fp32
// (log2e folded into Q scale), pack to fp16 in LDS (wave-private region,
// no barrier), O = A.V via mfma.
// QKV interleaved per token: [t][0:2048]=Q, [2048:4096]=K, [4096:6144]=V.
__global__ __launch_bounds__(256) void attn_mfma(
    const _Float16* __restrict__ QKV, _Float16* __restrict__ Oh)
{
    __shared__ _Float16 Vt[8][264];      // V transposed [d][g], padded
    __shared__ _Float16 Al[256][72];     // exp(S) [h][g-chunk 64], padded (36 KB)
    __shared__ _Float16 Ot[256][8];      // O bounce [h][d]

    const int tid  = threadIdx.x;
    const int lane = tid & 63;
    const int wv   = tid >> 6;
    const int col  = lane & 15;
    const int quad = lane >> 4;
    const int hbase = wv * 64;

    #pragma unroll 1
    for (int tt = 0; tt < 2; ++tt) {
        const int t = blockIdx.x * 2 + tt;
        const _Float16* qb = QKV + (size_t)t * (3 * DM);
        const _Float16* kb = qb + DM;
        const _Float16* vb = qb + 2 * DM;

        __syncthreads();   // protect Vt overwrite vs previous token's readers

        {
            const f16x8 v = *(const f16x8*)(vb + tid * 8);
            #pragma unroll
            for (int d = 0; d < 8; ++d) Vt[d][tid] = v[d];
        }

        f16x8 qf[4];
        #pragma unroll
        for (int ht = 0; ht < 4; ++ht) {
            f16x8 v = {};
            if (quad == 0)
                v = *(const f16x8*)(qb + (hbase + ht * 16 + col) * 8);
            #pragma unroll
            for (int j = 0; j < 8; ++j) qf[ht][j] = v[j] * (_Float16)(SCALE * LOG2E);
        }

        __syncthreads();   // Vt visible to all waves

        const f32x4 zf = {};
        float rsum[4] = {};
        f32x4 oacc[4] = {};

        #pragma unroll 1
        for (int c = 0; c < 4; ++c) {
            const int gchunk = c * 64;

            f16x8 kf[4];
            #pragma unroll
            for (int gt = 0; gt < 4; ++gt) {
                f16x8 v = {};
                if (quad == 0)
                    v = *(const f16x8*)(kb + (gchunk + gt * 16 + col) * 8);
                kf[gt] = v;
            }

            f32x4 s[4][4];
            #pragma unroll
            for (int gt = 0; gt < 4; ++gt)
                #pragma unroll
                for (int ht = 0; ht < 4; ++ht)
                    s[gt][ht] = __builtin_amdgcn_mfma_f32_16x16x32_f16(kf[gt], qf[ht], zf, 0, 0, 0);

            #pragma unroll
            for (int gt = 0; gt < 4; ++gt) {
                #pragma unroll
                for (int ht = 0; ht < 4; ++ht) {
                    f16x4 e4;
                    #pragma unroll
                    for (int r = 0; r < 4; ++r) {
                        e4[r] = (_Float16)EXP2(s[gt][ht][r]);
                        rsum[ht] += (float)e4[r];
                    }
                    *(f16x4*)&Al[hbase + ht * 16 + col][gt * 16 + quad * 4] = e4;
                }
            }

            #pragma unroll
            for (int ks = 0; ks < 2; ++ks) {
                f16x8 vf = {};
                if (col < 8)
                    vf = *(const f16x8*)&Vt[col][gchunk + ks * 32 + quad * 8];
                #pragma unroll
                for (int ht = 0; ht < 4; ++ht) {
                    const f16x8 af = *(const f16x8*)&Al[hbase + ht * 16 + col][ks * 32 + quad * 8];
                    oacc[ht] = __builtin_amdgcn_mfma_f32_16x16x32_f16(af, vf, oacc[ht], 0, 0, 0);
                }
            }
        }

        #pragma unroll
        for (int ht = 0; ht < 4; ++ht) {
            rsum[ht] += __shfl_xor(rsum[ht], 16, 64);
            rsum[ht] += __shfl_xor(rsum[ht], 32, 64);
        }

        #pragma unroll
        for (int ht = 0; ht < 4; ++ht) {
            #pragma unroll
            for (int r = 0; r < 4; ++r) {
                const float sh = __shfl(rsum[ht], quad * 4 + r, 64);
                const float v  = oacc[ht][r] / sh;
                if (col < 8)
                    Ot[hbase + ht * 16 + quad * 4 + r][col] = (_Float16)v;
            }
        }
        const f16x8 ov = *(const f16x8*)&Ot[tid][0];   // same-wave rows: no barrier
        *(f16x8*)(Oh + (size_t)t * DM + tid * 8) = ov;
    }
}

// ---------------------------------------------------------------------------
extern "C" void kernel_launch(void* const* d_in, const int* in_sizes, int n_in,
                              void* d_out, int out_size, void* d_ws, size_t ws_size,
                              hipStream_t stream)
{
    const float* x  = (const float*)d_in[0];
    // d_in[1] = phase_shift: cancels analytically (cos^2 + sin^2 = 1), unused
    const float* Wq = (const float*)d_in[2];
    const float* bq = (const float*)d_in[3];
    const float* Wk = (const float*)d_in[4];
    const float* bk = (const float*)d_in[5];
    const float* Wv = (const float*)d_in[6];
    const float* bv = (const float*)d_in[7];
    const float* Wo = (const float*)d_in[8];
    const float* bo = (const float*)d_in[9];
    float* out = (float*)d_out;

    char* ws = (char*)d_ws;
    _Float16* xh  = (_Float16*)(ws);                 // 4 MB  [1024][2048]
    _Float16* Wt  = (_Float16*)(ws + (4u  << 20));   // 24 MB fused B^T [6144][2048] (q|k|v)
    _Float16* Wto = (_Float16*)(ws + (28u << 20));   // 8 MB
    _Float16* QKV = (_Float16*)(ws + (36u << 20));   // 12 MB [1024][6144] (q|k|v per token)
    _Float16* Oh  = (_Float16*)(ws + (48u << 20));   // 4 MB

    // cast x + cast/transpose 4 weights in one launch (q,k,v land contiguous)
    prep<<<dim3(32, 32, 5), dim3(256), 0, stream>>>(
        x, xh, Wq, Wk, Wv, Wo,
        Wt, Wt + 2048 * 2048, Wt + 2 * 2048 * 2048, Wto);

    // QKV as ONE fused-N GEMM: M=1024, N=6144, K=2048. Tile 128x192,
    // 8 waves (wave tile 64x48), 3 LDS buffers (120 KB), depth 2.
    // Grid 32x8 = 256 blocks = exactly 1/CU.
    gemm_p3<2, 4, 4, 3, true, 3 * DM, true, 3><<<dim3(32, 8), dim3(512), 0, stream>>>(
        xh, Wt, bq, bk, bv, (void*)QKV);

    attn_mfma<<<dim3(M_TOK / 2), dim3(256), 0, stream>>>(QKV, Oh);

    // output projection: M=1024, N=2048, K=2048. Tile 64x128, 8 waves
    // (wave tile 32x32), 4 buffers (96 KB), depth 3 (vmcnt steady = 6).
    // Grid 16x16 = 256 blocks = exactly 1/CU.
    gemm_p3<2, 4, 2, 2, false, DM, false, 4><<<dim3(16, 16), dim3(512), 0, stream>>>(
        Oh, Wto, bo, bo, bo, (void*)out);
}